// Round 1
// baseline (311.572 us; speedup 1.0000x reference)
//
#include <hip/hip_runtime.h>
#include <cfloat>

typedef unsigned short u16;
typedef unsigned int   u32;
typedef __attribute__((ext_vector_type(8))) short short8;
typedef __attribute__((ext_vector_type(4))) float float4_;

#define NB   2
#define N1   4096
#define N2   32768
#define C1   128
#define C2   64
#define CIN  192      // C1 + C2
#define F1   128
#define F2   128
#define ROW0 131      // 3 + C1 (fp32)
#define ROW1 67       // 3 + C2 (fp32)
#define NQ   (NB * N2)   // 65536 total query points
#define EPSF 1e-07f
#define KSPLIT 2
#define KCH  (N1 / KSPLIT)   // 2048 candidates per tile
#define PADX 200      // LDS x-tile pitch (u16)
#define PADH 136      // LDS h-tile pitch (u16)

// round-to-nearest-even fp32 -> bf16 (finite data only)
__device__ __forceinline__ u16 f2bf(float f) {
  u32 x = __float_as_uint(f);
  return (u16)((x + 0x7fffu + ((x >> 16) & 1u)) >> 16);
}

// BRANCHLESS stable top-3 insert. Strict <: earlier index wins ties (lax.top_k).
__device__ __forceinline__ void ins3b(float d, int gi,
    float& d0, float& d1, float& d2, int& i0, int& i1, int& i2) {
  bool lt0 = d < d0, lt1 = d < d1, lt2 = d < d2;
  d2 = lt1 ? d1 : (lt2 ? d : d2);
  i2 = lt1 ? i1 : (lt2 ? gi : i2);
  d1 = lt0 ? d0 : (lt1 ? d : d1);
  i1 = lt0 ? i0 : (lt1 ? gi : i1);
  d0 = lt0 ? d : d0;
  i0 = lt0 ? gi : i0;
}

struct Part { float d0, d1, d2; int i0, i1, i2; };   // 24 B
struct KW   { int i0, i1, i2; float w0, w1, w2; };   // 24 B

// ---- repack: weights fp32 -> transposed bf16; candidate xyz -> packed float4 ---
__global__ void repack_w(const float* __restrict__ W1, const float* __restrict__ W2,
                         u16* __restrict__ W1t, u16* __restrict__ W2t,
                         const float* __restrict__ in0, float4* __restrict__ xyz1p) {
  int i = blockIdx.x * 256 + threadIdx.x;
  if (i < F1 * CIN) { int n = i / CIN, k = i % CIN; W1t[i] = f2bf(W1[k * F1 + n]); }
  if (i < F2 * F1)  { int n = i / F1,  k = i % F1;  W2t[i] = f2bf(W2[k * F2 + n]); }
  if (i < NB * N1)  {
    const float* r = in0 + (size_t)i * ROW0;
    xyz1p[i] = make_float4(r[0], r[1], r[2], 0.f);
  }
}

// ---- K1: kNN partial top-3 over one 2048-candidate tile ------------------------
// grid (NQ/256, KSPLIT) = 512 blocks -> 2 blocks/CU, 8 waves/CU, 2 waves/SIMD.
// LDS 32 KB/block. Wave-uniform early-out on d<d2: after warm-up ~68% of
// iterations skip the 13-instr insert (slow-path fraction ~= (192+192*ln(T/192))/T).
__global__ __launch_bounds__(256) void knn_part(const float4* __restrict__ xyz1p,
                                                const float* __restrict__ in1,
                                                Part* __restrict__ part) {
  __shared__ __align__(16) float4 cs[KCH];   // 32 KB
  int t = threadIdx.x;
  int q = blockIdx.x * 256 + t;
  int ct = blockIdx.y;
  int b = q >> 15;                            // uniform per block
  int c0 = ct * KCH;
  const float4* src = xyz1p + b * N1 + c0;
  for (int j = t; j < KCH; j += 256) cs[j] = src[j];
  __syncthreads();
  int n = q & (N2 - 1);
  const float* qr = in1 + (size_t)(b * N2 + n) * ROW1;
  float qx = qr[0], qy = qr[1], qz = qr[2];
  float d0 = FLT_MAX, d1 = FLT_MAX, d2 = FLT_MAX;
  int   i0 = 0, i1 = 0, i2 = 0;
#pragma unroll 8
  for (int j = 0; j < KCH; j++) {
    float4 cc = cs[j];                        // wave-uniform: LDS broadcast
    float dx = qx - cc.x, dy = qy - cc.y, dz = qz - cc.z;
    // exact numpy order, no FMA contraction: (dx^2 + dy^2) + dz^2
    float d = __fadd_rn(__fadd_rn(__fmul_rn(dx, dx), __fmul_rn(dy, dy)),
                        __fmul_rn(dz, dz));
    // wave-uniform skip: insert is a no-op for every lane when no lane has d<d2.
    // Bit-identical to unconditional ins3b (strict <, ascending j).
    if (__any(d < d2)) {
      bool lt0 = d < d0, lt1 = d < d1, lt2 = d < d2;
      int gi = c0 + j;
      d2 = lt1 ? d1 : (lt2 ? d : d2);
      i2 = lt1 ? i1 : (lt2 ? gi : i2);
      d1 = lt0 ? d0 : (lt1 ? d : d1);
      i1 = lt0 ? i0 : (lt1 ? gi : i1);
      d0 = lt0 ? d : d0;
      i0 = lt0 ? gi : i0;
    }
  }
  Part p; p.d0 = d0; p.d1 = d1; p.d2 = d2; p.i0 = i0; p.i1 = i1; p.i2 = i2;
  part[((size_t)q << 1) + ct] = p;
}

// ---- K2: merge partials (ascending tile order preserves tie stability) ---------
__global__ __launch_bounds__(256) void knn_merge(const Part* __restrict__ part,
                                                 KW* __restrict__ kw) {
  int q = blockIdx.x * 256 + threadIdx.x;
  float d0 = FLT_MAX, d1 = FLT_MAX, d2 = FLT_MAX;
  int   i0 = 0, i1 = 0, i2 = 0;
#pragma unroll
  for (int ct = 0; ct < KSPLIT; ct++) {
    Part p = part[((size_t)q << 1) + ct];
    ins3b(p.d0, p.i0, d0, d1, d2, i0, i1, i2);
    ins3b(p.d1, p.i1, d0, d1, d2, i0, i1, i2);
    ins3b(p.d2, p.i2, d0, d1, d2, i0, i1, i2);
  }
  float a0 = fmaxf(d0, EPSF), a1 = fmaxf(d1, EPSF), a2 = fmaxf(d2, EPSF);
  float w0 = 1.f / a0, w1 = 1.f / a1, w2 = 1.f / a2;
  float s = __fadd_rn(__fadd_rn(w0, w1), w2);
  KW o; o.i0 = i0; o.i1 = i1; o.i2 = i2;
  o.w0 = w0 / s; o.w1 = w1 / s; o.w2 = w2 / s;
  kw[q] = o;
}

// ---- K3: interp + concat -> bf16 LDS -> MFMA MLP1 -> MFMA MLP2 -> fp32 out -----
// block = 256 = 4 waves; each wave owns 16 query rows. 1024 blocks.
__global__ __launch_bounds__(256) void interp_mlp(
    const float* __restrict__ in0, const float* __restrict__ in1,
    const KW* __restrict__ kw,
    const u16* __restrict__ W1t, const float* __restrict__ b1,
    const u16* __restrict__ W2t, const float* __restrict__ b2,
    float* __restrict__ out) {
  __shared__ __align__(16) u16 xs[4][16][PADX];   // 25,600 B
  __shared__ __align__(16) u16 hs[4][16][PADH];   // 17,408 B
  int t = threadIdx.x;
  int wave = t >> 6, lane = t & 63;
  int l16 = lane & 15, quad = lane >> 4;
  int qbase = blockIdx.x * 64 + wave * 16;
  int b = qbase >> 15;                  // uniform per block

  // interp + concat into xs[wave] (16 x 192), fp32 gather, bf16 pack
  for (int qi = 0; qi < 16; qi++) {
    int q = qbase + qi;
    KW k = kw[q];                       // wave-uniform load
    const float* base = in0 + (size_t)b * N1 * ROW0 + 3;
    const float* r0 = base + (size_t)k.i0 * ROW0;
    const float* r1 = base + (size_t)k.i1 * ROW0;
    const float* r2 = base + (size_t)k.i2 * ROW0;
    float lo = __fadd_rn(__fadd_rn(__fmul_rn(k.w0, r0[lane]),
                                   __fmul_rn(k.w1, r1[lane])),
                         __fmul_rn(k.w2, r2[lane]));
    float hi = __fadd_rn(__fadd_rn(__fmul_rn(k.w0, r0[64 + lane]),
                                   __fmul_rn(k.w1, r1[64 + lane])),
                         __fmul_rn(k.w2, r2[64 + lane]));
    xs[wave][qi][lane]      = f2bf(lo);
    xs[wave][qi][64 + lane] = f2bf(hi);
    int n2 = q & (N2 - 1);              // channels 128..191 = points2
    xs[wave][qi][C1 + lane] = f2bf(in1[(size_t)(b * N2 + n2) * ROW1 + 3 + lane]);
  }
  __syncthreads();

  // GEMM1: h = relu(x @ W1 + b1); A from LDS, B from global (L1/L2-resident)
  float4_ acc[8];
#pragma unroll
  for (int nt = 0; nt < 8; nt++) acc[nt] = (float4_)0.f;
#pragma unroll
  for (int k0 = 0; k0 < CIN; k0 += 32) {
    short8 af = *(const short8*)&xs[wave][l16][k0 + quad * 8];
#pragma unroll
    for (int nt = 0; nt < 8; nt++) {
      short8 bf = *(const short8*)(W1t + (size_t)(nt * 16 + l16) * CIN + k0 + quad * 8);
      acc[nt] = __builtin_amdgcn_mfma_f32_16x16x32_bf16(af, bf, acc[nt], 0, 0, 0);
    }
  }
#pragma unroll
  for (int nt = 0; nt < 8; nt++) {
    float bv = b1[nt * 16 + l16];
#pragma unroll
    for (int r = 0; r < 4; r++) {   // C/D: row=quad*4+r, col=nt*16+l16
      hs[wave][quad * 4 + r][nt * 16 + l16] = f2bf(fmaxf(acc[nt][r] + bv, 0.f));
    }
  }
  __syncthreads();

  // GEMM2: y = relu(h @ W2 + b2) -> fp32 global store
  float4_ a2[8];
#pragma unroll
  for (int nt = 0; nt < 8; nt++) a2[nt] = (float4_)0.f;
#pragma unroll
  for (int k0 = 0; k0 < F1; k0 += 32) {
    short8 af = *(const short8*)&hs[wave][l16][k0 + quad * 8];
#pragma unroll
    for (int nt = 0; nt < 8; nt++) {
      short8 bf = *(const short8*)(W2t + (size_t)(nt * 16 + l16) * F1 + k0 + quad * 8);
      a2[nt] = __builtin_amdgcn_mfma_f32_16x16x32_bf16(af, bf, a2[nt], 0, 0, 0);
    }
  }
#pragma unroll
  for (int nt = 0; nt < 8; nt++) {
    float bv = b2[nt * 16 + l16];
#pragma unroll
    for (int r = 0; r < 4; r++) {
      int row = qbase + quad * 4 + r;
      out[(size_t)row * F2 + nt * 16 + l16] = fmaxf(a2[nt][r] + bv, 0.f);
    }
  }
}

// ---- K4: xyz2 passthrough fp32 -> fp32 -----------------------------------------
__global__ void xyz_copy(const float* __restrict__ in1, float* __restrict__ out) {
  int q = blockIdx.x * blockDim.x + threadIdx.x;
  if (q < NQ) {
    const float* r = in1 + (size_t)q * ROW1;
    float* o = out + (size_t)NQ * F2 + (size_t)q * 3;
    o[0] = r[0]; o[1] = r[1]; o[2] = r[2];
  }
}

extern "C" void kernel_launch(void* const* d_in, const int* in_sizes, int n_in,
                              void* d_out, int out_size, void* d_ws, size_t ws_size,
                              hipStream_t stream) {
  // input assignment by element count (ordering-invariant); positional fallback
  const float *in0 = nullptr, *in1 = nullptr, *W1 = nullptr, *W2 = nullptr;
  const float *b1 = nullptr, *b2 = nullptr;
  for (int i = 0; i < n_in; i++) {
    const float* p = (const float*)d_in[i];
    switch (in_sizes[i]) {
      case 2 * N1 * ROW0: in0 = p; break;
      case 2 * N2 * ROW1: in1 = p; break;
      case CIN * F1:      W1  = p; break;
      case F1 * F2:       W2  = p; break;
      case F1:            (b1 ? b2 : b1) = p; break;
      default: break;
    }
  }
  if (!in0) in0 = (const float*)d_in[0];
  if (!in1) in1 = (const float*)d_in[1];
  if (!W1)  W1  = (const float*)d_in[2];
  if (!b1)  b1  = (const float*)d_in[3];
  if (!W2)  W2  = (const float*)d_in[4];
  if (!b2)  b2  = (const float*)d_in[5];

  float* out = (float*)d_out;   // fp32: x (65536*128) ++ xyz2 (65536*3)

  // ws: W1t 49,152 | W2t 32,768 | xyz1p 131,072 | kw 1,572,864 | part 3,145,728
  char* ws = (char*)d_ws;
  u16*    W1t   = (u16*)(ws + 0);
  u16*    W2t   = (u16*)(ws + 49152);
  float4* xyz1p = (float4*)(ws + 81920);
  KW*     kw    = (KW*)(ws + 212992);
  Part*   part  = (Part*)(ws + 1785856);

  repack_w<<<dim3(96), dim3(256), 0, stream>>>(W1, W2, W1t, W2t, in0, xyz1p);
  knn_part<<<dim3(NQ / 256, KSPLIT), dim3(256), 0, stream>>>(xyz1p, in1, part);
  knn_merge<<<dim3(NQ / 256), dim3(256), 0, stream>>>(part, kw);
  interp_mlp<<<dim3(NQ / 64), dim3(256), 0, stream>>>(in0, in1, kw, W1t, b1, W2t, b2, out);
  xyz_copy<<<dim3((NQ + 255) / 256), dim3(256), 0, stream>>>(in1, out);
}

// Round 2
// 274.830 us; speedup vs baseline: 1.1337x; 1.1337x over previous
//
#include <hip/hip_runtime.h>
#include <cfloat>

typedef unsigned short u16;
typedef unsigned int   u32;
typedef __attribute__((ext_vector_type(8))) short short8;
typedef __attribute__((ext_vector_type(4))) float float4_;

#define NB   2
#define N1   4096
#define N2   32768
#define C1   128
#define C2   64
#define CIN  192      // C1 + C2
#define F1   128
#define F2   128
#define ROW0 131      // 3 + C1 (fp32)
#define ROW1 67       // 3 + C2 (fp32)
#define NQ   (NB * N2)   // 65536 total query points
#define EPSF 1e-07f
#define KSPLIT 4
#define KCH  (N1 / KSPLIT)   // 1024 candidates per tile
#define PADX 200      // LDS x-tile pitch (u16)
#define PADH 136      // LDS h-tile pitch (u16)

// round-to-nearest-even fp32 -> bf16 (finite data only)
__device__ __forceinline__ u16 f2bf(float f) {
  u32 x = __float_as_uint(f);
  return (u16)((x + 0x7fffu + ((x >> 16) & 1u)) >> 16);
}

// BRANCHLESS stable top-3 insert (merge path). Strict <: earlier index wins ties.
__device__ __forceinline__ void ins3b(float d, int gi,
    float& d0, float& d1, float& d2, int& i0, int& i1, int& i2) {
  bool lt0 = d < d0, lt1 = d < d1, lt2 = d < d2;
  d2 = lt1 ? d1 : (lt2 ? d : d2);
  i2 = lt1 ? i1 : (lt2 ? gi : i2);
  d1 = lt0 ? d0 : (lt1 ? d : d1);
  i1 = lt0 ? i0 : (lt1 ? gi : i1);
  d0 = lt0 ? d : d0;
  i0 = lt0 ? gi : i0;
}

struct Part { float d0, d1, d2; int i0, i1, i2; };   // 24 B
struct KW   { int i0, i1, i2; float w0, w1, w2; };   // 24 B

// ---- repack: weights fp32 -> transposed bf16; candidate xyz -> packed float4 ---
__global__ void repack_w(const float* __restrict__ W1, const float* __restrict__ W2,
                         u16* __restrict__ W1t, u16* __restrict__ W2t,
                         const float* __restrict__ in0, float4* __restrict__ xyz1p) {
  int i = blockIdx.x * 256 + threadIdx.x;
  if (i < F1 * CIN) { int n = i / CIN, k = i % CIN; W1t[i] = f2bf(W1[k * F1 + n]); }
  if (i < F2 * F1)  { int n = i / F1,  k = i % F1;  W2t[i] = f2bf(W2[k * F2 + n]); }
  if (i < NB * N1)  {
    const float* r = in0 + (size_t)i * ROW0;
    xyz1p[i] = make_float4(r[0], r[1], r[2], 0.f);
  }
}

// ---- K1: kNN partial top-3 over one 1024-candidate tile ------------------------
// grid (NQ/256, KSPLIT) = 1024 blocks -> 4 blocks/CU, 16 waves/CU, 4 waves/SIMD.
// NO LDS: candidate base address is uniform (blockIdx-only) so the compiler
// promotes candidate loads to s_load into SGPRs (scalar pipe, zero VALU slots).
// Top-3 distances via v_min/v_med3 (3 instrs); indices via 3 cmp + 5 cndmask.
// Per iter: 8 dist + 11 insert = 19 VALU, 0 vector-mem, no branches.
__global__ __launch_bounds__(256) void knn_part(const float4* __restrict__ xyz1p,
                                                const float* __restrict__ in1,
                                                Part* __restrict__ part) {
  int t = threadIdx.x;
  int bb = blockIdx.x >> 7;                   // batch: uniform, threadIdx-free
  int ct = blockIdx.y;
  int c0 = ct * KCH;
  const float4* __restrict__ src = xyz1p + (size_t)bb * N1 + c0;  // uniform base
  int q = blockIdx.x * 256 + t;
  int n = q & (N2 - 1);
  const float* qr = in1 + (size_t)(bb * N2 + n) * ROW1;
  float qx = qr[0], qy = qr[1], qz = qr[2];
  float d0 = FLT_MAX, d1 = FLT_MAX, d2 = FLT_MAX;
  int   i0 = 0, i1 = 0, i2 = 0;
#pragma unroll 8
  for (int j = 0; j < KCH; j++) {
    float4 cc = src[j];                       // uniform -> s_load (SGPR broadcast)
    float dx = qx - cc.x, dy = qy - cc.y, dz = qz - cc.z;
    // exact numpy order, no FMA contraction: (dx^2 + dy^2) + dz^2
    float d = __fadd_rn(__fadd_rn(__fmul_rn(dx, dx), __fmul_rn(dy, dy)),
                        __fmul_rn(dz, dz));
    int gi = c0 + j;                          // uniform (scalar pipe)
    bool lt0 = d < d0, lt1 = d < d1, lt2 = d < d2;
    // indices: 5 cndmask (gi is SGPR operand, legal: 1 sgpr/instr)
    i2 = lt1 ? i1 : (lt2 ? gi : i2);
    i1 = lt0 ? i0 : (lt1 ? gi : i1);
    i0 = lt0 ? gi : i0;
    // values: min/med3 sorting network, equivalent to stable insert for values.
    // d0'=min(d,d0); d1'=med3(d0,d,d1); d2'=med3(d,d1,d2)  (verified all cases)
    float nd0 = fminf(d, d0);
    float nd1 = __builtin_amdgcn_fmed3f(d0, d, d1);
    float nd2 = __builtin_amdgcn_fmed3f(d, d1, d2);
    d0 = nd0; d1 = nd1; d2 = nd2;
  }
  Part p; p.d0 = d0; p.d1 = d1; p.d2 = d2; p.i0 = i0; p.i1 = i1; p.i2 = i2;
  part[((size_t)q << 2) + ct] = p;
}

// ---- K2: merge partials (ascending tile order preserves tie stability) ---------
__global__ __launch_bounds__(256) void knn_merge(const Part* __restrict__ part,
                                                 KW* __restrict__ kw) {
  int q = blockIdx.x * 256 + threadIdx.x;
  float d0 = FLT_MAX, d1 = FLT_MAX, d2 = FLT_MAX;
  int   i0 = 0, i1 = 0, i2 = 0;
#pragma unroll
  for (int ct = 0; ct < KSPLIT; ct++) {
    Part p = part[((size_t)q << 2) + ct];
    ins3b(p.d0, p.i0, d0, d1, d2, i0, i1, i2);
    ins3b(p.d1, p.i1, d0, d1, d2, i0, i1, i2);
    ins3b(p.d2, p.i2, d0, d1, d2, i0, i1, i2);
  }
  float a0 = fmaxf(d0, EPSF), a1 = fmaxf(d1, EPSF), a2 = fmaxf(d2, EPSF);
  float w0 = 1.f / a0, w1 = 1.f / a1, w2 = 1.f / a2;
  float s = __fadd_rn(__fadd_rn(w0, w1), w2);
  KW o; o.i0 = i0; o.i1 = i1; o.i2 = i2;
  o.w0 = w0 / s; o.w1 = w1 / s; o.w2 = w2 / s;
  kw[q] = o;
}

// ---- K3: interp + concat -> bf16 LDS -> MFMA MLP1 -> MFMA MLP2 -> fp32 out -----
// block = 256 = 4 waves; each wave owns 16 query rows. 1024 blocks.
__global__ __launch_bounds__(256) void interp_mlp(
    const float* __restrict__ in0, const float* __restrict__ in1,
    const KW* __restrict__ kw,
    const u16* __restrict__ W1t, const float* __restrict__ b1,
    const u16* __restrict__ W2t, const float* __restrict__ b2,
    float* __restrict__ out) {
  __shared__ __align__(16) u16 xs[4][16][PADX];   // 25,600 B
  __shared__ __align__(16) u16 hs[4][16][PADH];   // 17,408 B
  int t = threadIdx.x;
  int wave = t >> 6, lane = t & 63;
  int l16 = lane & 15, quad = lane >> 4;
  int qbase = blockIdx.x * 64 + wave * 16;
  int b = qbase >> 15;                  // uniform per block

  // interp + concat into xs[wave] (16 x 192), fp32 gather, bf16 pack
  for (int qi = 0; qi < 16; qi++) {
    int q = qbase + qi;
    KW k = kw[q];                       // wave-uniform load
    const float* base = in0 + (size_t)b * N1 * ROW0 + 3;
    const float* r0 = base + (size_t)k.i0 * ROW0;
    const float* r1 = base + (size_t)k.i1 * ROW0;
    const float* r2 = base + (size_t)k.i2 * ROW0;
    float lo = __fadd_rn(__fadd_rn(__fmul_rn(k.w0, r0[lane]),
                                   __fmul_rn(k.w1, r1[lane])),
                         __fmul_rn(k.w2, r2[lane]));
    float hi = __fadd_rn(__fadd_rn(__fmul_rn(k.w0, r0[64 + lane]),
                                   __fmul_rn(k.w1, r1[64 + lane])),
                         __fmul_rn(k.w2, r2[64 + lane]));
    xs[wave][qi][lane]      = f2bf(lo);
    xs[wave][qi][64 + lane] = f2bf(hi);
    int n2 = q & (N2 - 1);              // channels 128..191 = points2
    xs[wave][qi][C1 + lane] = f2bf(in1[(size_t)(b * N2 + n2) * ROW1 + 3 + lane]);
  }
  __syncthreads();

  // GEMM1: h = relu(x @ W1 + b1); A from LDS, B from global (L1/L2-resident)
  float4_ acc[8];
#pragma unroll
  for (int nt = 0; nt < 8; nt++) acc[nt] = (float4_)0.f;
#pragma unroll
  for (int k0 = 0; k0 < CIN; k0 += 32) {
    short8 af = *(const short8*)&xs[wave][l16][k0 + quad * 8];
#pragma unroll
    for (int nt = 0; nt < 8; nt++) {
      short8 bf = *(const short8*)(W1t + (size_t)(nt * 16 + l16) * CIN + k0 + quad * 8);
      acc[nt] = __builtin_amdgcn_mfma_f32_16x16x32_bf16(af, bf, acc[nt], 0, 0, 0);
    }
  }
#pragma unroll
  for (int nt = 0; nt < 8; nt++) {
    float bv = b1[nt * 16 + l16];
#pragma unroll
    for (int r = 0; r < 4; r++) {   // C/D: row=quad*4+r, col=nt*16+l16
      hs[wave][quad * 4 + r][nt * 16 + l16] = f2bf(fmaxf(acc[nt][r] + bv, 0.f));
    }
  }
  __syncthreads();

  // GEMM2: y = relu(h @ W2 + b2) -> fp32 global store
  float4_ a2[8];
#pragma unroll
  for (int nt = 0; nt < 8; nt++) a2[nt] = (float4_)0.f;
#pragma unroll
  for (int k0 = 0; k0 < F1; k0 += 32) {
    short8 af = *(const short8*)&hs[wave][l16][k0 + quad * 8];
#pragma unroll
    for (int nt = 0; nt < 8; nt++) {
      short8 bf = *(const short8*)(W2t + (size_t)(nt * 16 + l16) * F1 + k0 + quad * 8);
      a2[nt] = __builtin_amdgcn_mfma_f32_16x16x32_bf16(af, bf, a2[nt], 0, 0, 0);
    }
  }
#pragma unroll
  for (int nt = 0; nt < 8; nt++) {
    float bv = b2[nt * 16 + l16];
#pragma unroll
    for (int r = 0; r < 4; r++) {
      int row = qbase + quad * 4 + r;
      out[(size_t)row * F2 + nt * 16 + l16] = fmaxf(a2[nt][r] + bv, 0.f);
    }
  }
}

// ---- K4: xyz2 passthrough fp32 -> fp32 -----------------------------------------
__global__ void xyz_copy(const float* __restrict__ in1, float* __restrict__ out) {
  int q = blockIdx.x * blockDim.x + threadIdx.x;
  if (q < NQ) {
    const float* r = in1 + (size_t)q * ROW1;
    float* o = out + (size_t)NQ * F2 + (size_t)q * 3;
    o[0] = r[0]; o[1] = r[1]; o[2] = r[2];
  }
}

extern "C" void kernel_launch(void* const* d_in, const int* in_sizes, int n_in,
                              void* d_out, int out_size, void* d_ws, size_t ws_size,
                              hipStream_t stream) {
  // input assignment by element count (ordering-invariant); positional fallback
  const float *in0 = nullptr, *in1 = nullptr, *W1 = nullptr, *W2 = nullptr;
  const float *b1 = nullptr, *b2 = nullptr;
  for (int i = 0; i < n_in; i++) {
    const float* p = (const float*)d_in[i];
    switch (in_sizes[i]) {
      case 2 * N1 * ROW0: in0 = p; break;
      case 2 * N2 * ROW1: in1 = p; break;
      case CIN * F1:      W1  = p; break;
      case F1 * F2:       W2  = p; break;
      case F1:            (b1 ? b2 : b1) = p; break;
      default: break;
    }
  }
  if (!in0) in0 = (const float*)d_in[0];
  if (!in1) in1 = (const float*)d_in[1];
  if (!W1)  W1  = (const float*)d_in[2];
  if (!b1)  b1  = (const float*)d_in[3];
  if (!W2)  W2  = (const float*)d_in[4];
  if (!b2)  b2  = (const float*)d_in[5];

  float* out = (float*)d_out;   // fp32: x (65536*128) ++ xyz2 (65536*3)

  // ws: W1t 49,152 | W2t 32,768 | xyz1p 131,072 | kw 1,572,864 | part 6,291,456
  char* ws = (char*)d_ws;
  u16*    W1t   = (u16*)(ws + 0);
  u16*    W2t   = (u16*)(ws + 49152);
  float4* xyz1p = (float4*)(ws + 81920);
  KW*     kw    = (KW*)(ws + 212992);
  Part*   part  = (Part*)(ws + 1785856);

  repack_w<<<dim3(96), dim3(256), 0, stream>>>(W1, W2, W1t, W2t, in0, xyz1p);
  knn_part<<<dim3(NQ / 256, KSPLIT), dim3(256), 0, stream>>>(xyz1p, in1, part);
  knn_merge<<<dim3(NQ / 256), dim3(256), 0, stream>>>(part, kw);
  interp_mlp<<<dim3(NQ / 64), dim3(256), 0, stream>>>(in0, in1, kw, W1t, b1, W2t, b2, out);
  xyz_copy<<<dim3((NQ + 255) / 256), dim3(256), 0, stream>>>(in1, out);
}

// Round 4
// 258.713 us; speedup vs baseline: 1.2043x; 1.0623x over previous
//
#include <hip/hip_runtime.h>
#include <cfloat>

typedef unsigned short u16;
typedef unsigned int   u32;
typedef __attribute__((ext_vector_type(8))) short short8;
typedef __attribute__((ext_vector_type(4))) float float4_;

#define NB   2
#define N1   4096
#define N2   32768
#define C1   128
#define C2   64
#define CIN  192      // C1 + C2
#define F1   128
#define F2   128
#define ROW0 131      // 3 + C1 (fp32)
#define ROW1 67       // 3 + C2 (fp32)
#define NQ   (NB * N2)   // 65536 total query points
#define EPSF 1e-07f
#define KSPLIT 8
#define KCH  (N1 / KSPLIT)   // 512 candidates per tile
#define PADX 200      // LDS x-tile pitch (u16)
#define PADH 136      // LDS h-tile pitch (u16)

// round-to-nearest-even fp32 -> bf16 (finite data only)
__device__ __forceinline__ u16 f2bf(float f) {
  u32 x = __float_as_uint(f);
  return (u16)((x + 0x7fffu + ((x >> 16) & 1u)) >> 16);
}

// BRANCHLESS stable top-3 insert (merge path only). Strict <: earlier index wins.
__device__ __forceinline__ void ins3b(float d, int gi,
    float& d0, float& d1, float& d2, int& i0, int& i1, int& i2) {
  bool lt0 = d < d0, lt1 = d < d1, lt2 = d < d2;
  d2 = lt1 ? d1 : (lt2 ? d : d2);
  i2 = lt1 ? i1 : (lt2 ? gi : i2);
  d1 = lt0 ? d0 : (lt1 ? d : d1);
  i1 = lt0 ? i0 : (lt1 ? gi : i1);
  d0 = lt0 ? d : d0;
  i0 = lt0 ? gi : i0;
}

struct Part { float d0, d1, d2; int i0, i1, i2; };   // 24 B
struct KW   { int i0, i1, i2; float w0, w1, w2; };   // 24 B

// ---- repack: weights fp32 -> transposed bf16; candidate xyz -> packed float4 ---
__global__ void repack_w(const float* __restrict__ W1, const float* __restrict__ W2,
                         u16* __restrict__ W1t, u16* __restrict__ W2t,
                         const float* __restrict__ in0, float4* __restrict__ xyz1p) {
  int i = blockIdx.x * 256 + threadIdx.x;
  if (i < F1 * CIN) { int n = i / CIN, k = i % CIN; W1t[i] = f2bf(W1[k * F1 + n]); }
  if (i < F2 * F1)  { int n = i / F1,  k = i % F1;  W2t[i] = f2bf(W2[k * F2 + n]); }
  if (i < NB * N1)  {
    const float* r = in0 + (size_t)i * ROW0;
    xyz1p[i] = make_float4(r[0], r[1], r[2], 0.f);
  }
}

// ---- K1: kNN partial top-3, 512-candidate tile, exact 20-VALU inner loop -------
// grid (NQ/256, KSPLIT) = 2048 blocks -> 8 blocks/CU, 32 waves/CU (occupancy max).
// Candidates come from SGPRs (uniform s_load). Inner loop forced via inline asm:
//   8 dist (subrev/mul/add, RN, no FMA — bit-identical to reference order)
// + 3 v_cmp_nlt (inverted polarity, mask in vcc)
// + 5 v_cndmask (all-VGPR + vcc: exactly 1 constant-bus read — gi MUST be VGPR,
//   since cndmask's vcc operand is an explicit SGPR-pair read on the const bus)
// + v_min + 2 v_med3 (value sorting network == stable insert) + 1 v_mov for gi.
// Also writes xyz2 passthrough from ct==0 blocks (replaces xyz_copy kernel).
__global__ __launch_bounds__(256) void knn_part(const float4* __restrict__ xyz1p,
                                                const float* __restrict__ in1,
                                                Part* __restrict__ part,
                                                float* __restrict__ out) {
  int t = threadIdx.x;
  int bb = blockIdx.x >> 7;                   // batch: uniform, threadIdx-free
  int ct = blockIdx.y;
  int c0 = ct * KCH;
  const float4* __restrict__ src = xyz1p + (size_t)bb * N1 + c0;  // uniform base
  int q = blockIdx.x * 256 + t;
  int n = q & (N2 - 1);
  const float* qr = in1 + (size_t)(bb * N2 + n) * ROW1;
  float qx = qr[0], qy = qr[1], qz = qr[2];
  if (ct == 0) {                              // xyz2 passthrough (was xyz_copy)
    float* o = out + (size_t)NQ * F2 + (size_t)q * 3;
    o[0] = qx; o[1] = qy; o[2] = qz;
  }
  float d0 = FLT_MAX, d1 = FLT_MAX, d2 = FLT_MAX;
  int   i0 = 0, i1 = 0, i2 = 0;
#pragma unroll 8
  for (int j = 0; j < KCH; j++) {
    float4 cc = src[j];                       // uniform -> s_load (SGPR broadcast)
    int gi = c0 + j;                          // scalar; "v" constraint -> v_mov
    float dx, dy, dz, vd; int tm;
    asm("v_subrev_f32 %[dx], %[cx], %[qx]\n\t"      // dx = qx - cx
        "v_subrev_f32 %[dy], %[cy], %[qy]\n\t"
        "v_subrev_f32 %[dz], %[cz], %[qz]\n\t"
        "v_mul_f32 %[dx], %[dx], %[dx]\n\t"
        "v_mul_f32 %[dy], %[dy], %[dy]\n\t"
        "v_mul_f32 %[dz], %[dz], %[dz]\n\t"
        "v_add_f32 %[dx], %[dx], %[dy]\n\t"         // (dx^2 + dy^2)
        "v_add_f32 %[vd], %[dx], %[dz]\n\t"         // + dz^2  (exact ref order)
        "v_cmp_nlt_f32 vcc, %[vd], %[d2]\n\t"       // vcc = !(d<d2)
        "v_cndmask_b32 %[tm], %[gi], %[i2], vcc\n\t"  // t2 = lt2 ? gi : i2
        "v_cmp_nlt_f32 vcc, %[vd], %[d1]\n\t"       // vcc = !(d<d1)
        "v_cndmask_b32 %[i2], %[i1], %[tm], vcc\n\t"  // i2 = lt1 ? i1 : t2
        "v_cndmask_b32 %[tm], %[gi], %[i1], vcc\n\t"  // t1 = lt1 ? gi : i1
        "v_cmp_nlt_f32 vcc, %[vd], %[d0]\n\t"       // vcc = !(d<d0)
        "v_cndmask_b32 %[i1], %[i0], %[tm], vcc\n\t"  // i1 = lt0 ? i0 : t1
        "v_cndmask_b32 %[i0], %[gi], %[i0], vcc\n\t"  // i0 = lt0 ? gi : i0
        "v_med3_f32 %[d2], %[vd], %[d1], %[d2]\n\t"   // nd2 (uses old d1,d2)
        "v_med3_f32 %[d1], %[d0], %[vd], %[d1]\n\t"   // nd1 (uses old d0,d1)
        "v_min_f32 %[d0], %[vd], %[d0]"               // nd0
        : [d0]"+v"(d0), [d1]"+v"(d1), [d2]"+v"(d2),
          [i0]"+v"(i0), [i1]"+v"(i1), [i2]"+v"(i2),
          [dx]"=&v"(dx), [dy]"=&v"(dy), [dz]"=&v"(dz),
          [vd]"=&v"(vd), [tm]"=&v"(tm)
        : [qx]"v"(qx), [qy]"v"(qy), [qz]"v"(qz),
          [cx]"s"(cc.x), [cy]"s"(cc.y), [cz]"s"(cc.z), [gi]"v"(gi)
        : "vcc");
  }
  Part p; p.d0 = d0; p.d1 = d1; p.d2 = d2; p.i0 = i0; p.i1 = i1; p.i2 = i2;
  part[((size_t)q << 3) + ct] = p;
}

// ---- K2: merge partials (ascending tile order preserves tie stability) ---------
__global__ __launch_bounds__(256) void knn_merge(const Part* __restrict__ part,
                                                 KW* __restrict__ kw) {
  int q = blockIdx.x * 256 + threadIdx.x;
  float d0 = FLT_MAX, d1 = FLT_MAX, d2 = FLT_MAX;
  int   i0 = 0, i1 = 0, i2 = 0;
#pragma unroll
  for (int ct = 0; ct < KSPLIT; ct++) {
    Part p = part[((size_t)q << 3) + ct];
    ins3b(p.d0, p.i0, d0, d1, d2, i0, i1, i2);
    ins3b(p.d1, p.i1, d0, d1, d2, i0, i1, i2);
    ins3b(p.d2, p.i2, d0, d1, d2, i0, i1, i2);
  }
  float a0 = fmaxf(d0, EPSF), a1 = fmaxf(d1, EPSF), a2 = fmaxf(d2, EPSF);
  float w0 = 1.f / a0, w1 = 1.f / a1, w2 = 1.f / a2;
  float s = __fadd_rn(__fadd_rn(w0, w1), w2);
  KW o; o.i0 = i0; o.i1 = i1; o.i2 = i2;
  o.w0 = w0 / s; o.w1 = w1 / s; o.w2 = w2 / s;
  kw[q] = o;
}

// ---- K3: interp + concat -> bf16 LDS -> MFMA MLP1 -> MFMA MLP2 -> fp32 out -----
// block = 256 = 4 waves; each wave owns 16 query rows. 1024 blocks.
__global__ __launch_bounds__(256) void interp_mlp(
    const float* __restrict__ in0, const float* __restrict__ in1,
    const KW* __restrict__ kw,
    const u16* __restrict__ W1t, const float* __restrict__ b1,
    const u16* __restrict__ W2t, const float* __restrict__ b2,
    float* __restrict__ out) {
  __shared__ __align__(16) u16 xs[4][16][PADX];   // 25,600 B
  __shared__ __align__(16) u16 hs[4][16][PADH];   // 17,408 B
  int t = threadIdx.x;
  int wave = t >> 6, lane = t & 63;
  int l16 = lane & 15, quad = lane >> 4;
  int qbase = blockIdx.x * 64 + wave * 16;
  int b = qbase >> 15;                  // uniform per block

  // interp + concat into xs[wave] (16 x 192), fp32 gather, bf16 pack
  for (int qi = 0; qi < 16; qi++) {
    int q = qbase + qi;
    KW k = kw[q];                       // wave-uniform load
    const float* base = in0 + (size_t)b * N1 * ROW0 + 3;
    const float* r0 = base + (size_t)k.i0 * ROW0;
    const float* r1 = base + (size_t)k.i1 * ROW0;
    const float* r2 = base + (size_t)k.i2 * ROW0;
    float lo = __fadd_rn(__fadd_rn(__fmul_rn(k.w0, r0[lane]),
                                   __fmul_rn(k.w1, r1[lane])),
                         __fmul_rn(k.w2, r2[lane]));
    float hi = __fadd_rn(__fadd_rn(__fmul_rn(k.w0, r0[64 + lane]),
                                   __fmul_rn(k.w1, r1[64 + lane])),
                         __fmul_rn(k.w2, r2[64 + lane]));
    xs[wave][qi][lane]      = f2bf(lo);
    xs[wave][qi][64 + lane] = f2bf(hi);
    int n2 = q & (N2 - 1);              // channels 128..191 = points2
    xs[wave][qi][C1 + lane] = f2bf(in1[(size_t)(b * N2 + n2) * ROW1 + 3 + lane]);
  }
  __syncthreads();

  // GEMM1: h = relu(x @ W1 + b1); A from LDS, B from global (L1/L2-resident)
  float4_ acc[8];
#pragma unroll
  for (int nt = 0; nt < 8; nt++) acc[nt] = (float4_)0.f;
#pragma unroll
  for (int k0 = 0; k0 < CIN; k0 += 32) {
    short8 af = *(const short8*)&xs[wave][l16][k0 + quad * 8];
#pragma unroll
    for (int nt = 0; nt < 8; nt++) {
      short8 bf = *(const short8*)(W1t + (size_t)(nt * 16 + l16) * CIN + k0 + quad * 8);
      acc[nt] = __builtin_amdgcn_mfma_f32_16x16x32_bf16(af, bf, acc[nt], 0, 0, 0);
    }
  }
#pragma unroll
  for (int nt = 0; nt < 8; nt++) {
    float bv = b1[nt * 16 + l16];
#pragma unroll
    for (int r = 0; r < 4; r++) {   // C/D: row=quad*4+r, col=nt*16+l16
      hs[wave][quad * 4 + r][nt * 16 + l16] = f2bf(fmaxf(acc[nt][r] + bv, 0.f));
    }
  }
  __syncthreads();

  // GEMM2: y = relu(h @ W2 + b2) -> fp32 global store
  float4_ a2[8];
#pragma unroll
  for (int nt = 0; nt < 8; nt++) a2[nt] = (float4_)0.f;
#pragma unroll
  for (int k0 = 0; k0 < F1; k0 += 32) {
    short8 af = *(const short8*)&hs[wave][l16][k0 + quad * 8];
#pragma unroll
    for (int nt = 0; nt < 8; nt++) {
      short8 bf = *(const short8*)(W2t + (size_t)(nt * 16 + l16) * F1 + k0 + quad * 8);
      a2[nt] = __builtin_amdgcn_mfma_f32_16x16x32_bf16(af, bf, a2[nt], 0, 0, 0);
    }
  }
#pragma unroll
  for (int nt = 0; nt < 8; nt++) {
    float bv = b2[nt * 16 + l16];
#pragma unroll
    for (int r = 0; r < 4; r++) {
      int row = qbase + quad * 4 + r;
      out[(size_t)row * F2 + nt * 16 + l16] = fmaxf(a2[nt][r] + bv, 0.f);
    }
  }
}

extern "C" void kernel_launch(void* const* d_in, const int* in_sizes, int n_in,
                              void* d_out, int out_size, void* d_ws, size_t ws_size,
                              hipStream_t stream) {
  // input assignment by element count (ordering-invariant); positional fallback
  const float *in0 = nullptr, *in1 = nullptr, *W1 = nullptr, *W2 = nullptr;
  const float *b1 = nullptr, *b2 = nullptr;
  for (int i = 0; i < n_in; i++) {
    const float* p = (const float*)d_in[i];
    switch (in_sizes[i]) {
      case 2 * N1 * ROW0: in0 = p; break;
      case 2 * N2 * ROW1: in1 = p; break;
      case CIN * F1:      W1  = p; break;
      case F1 * F2:       W2  = p; break;
      case F1:            (b1 ? b2 : b1) = p; break;
      default: break;
    }
  }
  if (!in0) in0 = (const float*)d_in[0];
  if (!in1) in1 = (const float*)d_in[1];
  if (!W1)  W1  = (const float*)d_in[2];
  if (!b1)  b1  = (const float*)d_in[3];
  if (!W2)  W2  = (const float*)d_in[4];
  if (!b2)  b2  = (const float*)d_in[5];

  float* out = (float*)d_out;   // fp32: x (65536*128) ++ xyz2 (65536*3)

  // ws (13.58 MiB, proven size): W1t 49,152 | W2t 32,768 | kw 1,572,864 | part 12,582,912
  // xyz1p (131,072) ALIASES the kw region: repack writes it each iteration,
  // knn_part reads it, then knn_merge overwrites the region with kw (xyz1p dead).
  char* ws = (char*)d_ws;
  u16*    W1t   = (u16*)(ws + 0);
  u16*    W2t   = (u16*)(ws + 49152);
  float4* xyz1p = (float4*)(ws + 81920);      // alias of kw region
  KW*     kw    = (KW*)(ws + 81920);
  Part*   part  = (Part*)(ws + 1654784);

  repack_w<<<dim3(96), dim3(256), 0, stream>>>(W1, W2, W1t, W2t, in0, xyz1p);
  knn_part<<<dim3(NQ / 256, KSPLIT), dim3(256), 0, stream>>>(xyz1p, in1, part, out);
  knn_merge<<<dim3(NQ / 256), dim3(256), 0, stream>>>(part, kw);
  interp_mlp<<<dim3(NQ / 64), dim3(256), 0, stream>>>(in0, in1, kw, W1t, b1, W2t, b2, out);
}